// Round 1
// baseline (546.650 us; speedup 1.0000x reference)
//
#include <hip/hip_runtime.h>
#include <stdint.h>

typedef float  v4f __attribute__((ext_vector_type(4)));
typedef short  v4s __attribute__((ext_vector_type(4)));
typedef int    v4i __attribute__((ext_vector_type(4)));

#define LOG2E 1.44269504088896340736f
#define LN2   0.69314718055994530942f

static __device__ __forceinline__ float fexp2(float x){ return __builtin_amdgcn_exp2f(x); }
static __device__ __forceinline__ float flog2(float x){ return __builtin_amdgcn_logf(x); }

// pack two f32 -> two bf16 (round-half-up) in one dword via v_perm
static __device__ __forceinline__ unsigned pkbf(float a, float b){
  unsigned ua = __float_as_uint(a) + 0x8000u;
  unsigned ub = __float_as_uint(b) + 0x8000u;
  return __builtin_amdgcn_perm(ub, ua, 0x07060302u);
}
static __device__ __forceinline__ v4s pack4(const v4f& m){
  union { unsigned u[2]; v4s s; } t;
  t.u[0] = pkbf(m.x, m.y);
  t.u[1] = pkbf(m.z, m.w);
  return t.s;
}

static __device__ __forceinline__ v4f mfma16(v4s a, v4s b, v4f c){
#if __has_builtin(__builtin_amdgcn_mfma_f32_16x16x16bf16_1k)
  return __builtin_amdgcn_mfma_f32_16x16x16bf16_1k(a, b, c, 0, 0, 0);
#else
  v4f r = c;
  asm("s_nop 1\n\tv_mfma_f32_16x16x16_bf16 %0, %1, %2, %0\n\ts_nop 7\n\ts_nop 1"
      : "+v"(r) : "v"(a), "v"(b));
  return r;
#endif
}

// One wave per block. Wave handles 32 batches:
//  lane: n = lane&15 (MFMA row/col index), q = lane>>4, g = q>>1 (batch group),
//  qr = q&1 (state half), batch = 32*blk + 16*g + n, states r0..r0+3 (r0 = 4*qr).
// Recurrence (linear space): alpha' = (alpha . E) * exp(em_t), E = exp(transitions).
// MFMA computes D = A*B with A = blockdiag(E^T, E^T) (bf16, constant),
// B = alpha^T for the two batch groups. D (C-layout) == next B (B-layout) index map.
__global__ __launch_bounds__(64, 1)
void crf_fused(const float* __restrict__ em,
               const float* __restrict__ trans,
               const float* __restrict__ strt,
               const float* __restrict__ endt,
               const int*   __restrict__ tags,
               float* __restrict__ out)
{
  const int lane = threadIdx.x;
  const int n  = lane & 15;
  const int q  = lane >> 4;
  const int g  = q >> 1;
  const int qr = q & 1;
  const int r0 = qr << 2;
  const int b  = (blockIdx.x << 5) + (g << 4) + n;

  __shared__ float s_trans[64];
  __shared__ float s_start[8];
  __shared__ float s_end[8];
  s_trans[lane] = trans[lane];
  if (lane < 8){ s_start[lane] = strt[lane]; s_end[lane] = endt[lane]; }
  __syncthreads();

  // ---- constant A fragment: A[m][k], m = n (0..15), k = 4q + j ----
  v4s afrag;
  {
    const int m = n;
    float av[4];
#pragma unroll
    for (int j = 0; j < 4; ++j){
      const int k = (q << 2) + j;
      float v = 0.f;
      if (m < 8 && k < 8)        v = fexp2(s_trans[k * 8 + m] * LOG2E);          // E^T[m][k] = E[k][m]
      else if (m >= 8 && k >= 8) v = fexp2(s_trans[(k - 8) * 8 + (m - 8)] * LOG2E);
      av[j] = v;
    }
    union { unsigned u[2]; v4s s; } t;
    t.u[0] = pkbf(av[0], av[1]);
    t.u[1] = pkbf(av[2], av[3]);
    afrag = t.s;
  }

  const float* emb = em   + (size_t)b * (2048u * 8u) + (unsigned)r0;
  const int*   tgb = tags + (size_t)b * 2048u;

  v4f master = {0.f, 0.f, 0.f, 0.f};
  v4s bfrag  = {};
  float num = 0.f, logZ = 0.f;
  int prevtag = 0;

  v4f emA[16], emB[16];
  v4i tgA[4],  tgB[4];

  auto load_block = [&](int kb, v4f* E, v4i* T){
    const int t0 = kb << 4;
#pragma unroll
    for (int j = 0; j < 16; ++j)
      E[j] = *(const v4f*)(emb + (size_t)(t0 + j) * 8u);
#pragma unroll
    for (int i = 0; i < 4; ++i)
      T[i] = *(const v4i*)(tgb + t0 + (i << 2));
  };

  auto sel4 = [&](const v4f& e4, int s)->float{
    float a = (s & 1) ? e4.y : e4.x;
    float c = (s & 1) ? e4.w : e4.z;
    return (s & 2) ? c : a;
  };

  auto step = [&](const v4f& em4, int cur){
    v4f e;
    e.x = fexp2(em4.x * LOG2E); e.y = fexp2(em4.y * LOG2E);
    e.z = fexp2(em4.z * LOG2E); e.w = fexp2(em4.w * LOG2E);
    v4f zero = {0.f, 0.f, 0.f, 0.f};
    v4f d = mfma16(afrag, bfrag, zero);
    const bool m = (cur != 0);
    master.x = m ? d.x * e.x : master.x;
    master.y = m ? d.y * e.y : master.y;
    master.z = m ? d.z * e.z : master.z;
    master.w = m ? d.w * e.w : master.w;
    bfrag = pack4(master);
    // numerator: emission score (this lane's state half only) + transition score
    const int s = cur - 1;
    const float ev = sel4(em4, s);
    num += (m && ((s >> 2) == qr)) ? ev : 0.f;
    const float tv = s_trans[(((prevtag - 1) & 7) << 3) + (s & 7)];
    num += (m && (qr == 0)) ? tv : 0.f;
    if ((prevtag != 0) && (cur == 0) && (qr == 0)) num += s_end[prevtag - 1]; // rare: fires once per batch
    prevtag = cur;
  };

  auto init0 = [&](const v4f& em4, int cur){
    master.x = fexp2((s_start[r0 + 0] + em4.x) * LOG2E);
    master.y = fexp2((s_start[r0 + 1] + em4.y) * LOG2E);
    master.z = fexp2((s_start[r0 + 2] + em4.z) * LOG2E);
    master.w = fexp2((s_start[r0 + 3] + em4.w) * LOG2E);
    bfrag = pack4(master);
    const int s = cur - 1;                  // mask[0] always true (len >= 1024)
    const float ev = sel4(em4, s);
    num = ((s >> 2) == qr) ? (s_start[s & 7] + ev) : 0.f;
    prevtag = cur;
  };

  auto renorm = [&](){
    float mx = fmaxf(fmaxf(master.x, master.y), fmaxf(master.z, master.w));
    mx = fmaxf(mx, __shfl_xor(mx, 16, 64));   // column max across the two state halves
    const float inv = __builtin_amdgcn_rcpf(mx);
    master.x *= inv; master.y *= inv; master.z *= inv; master.w *= inv;
    logZ += flog2(mx);                        // logZ kept in log2 units
    bfrag = pack4(master);
  };

  auto process_block = [&](int kb, const v4f* E, const v4i* T){
#pragma unroll
    for (int j = 0; j < 16; ++j){
      const int cur = T[j >> 2][j & 3];
      if (j == 0 && kb == 0) init0(E[0], cur);
      else                   step(E[j], cur);
    }
    renorm();
  };

  load_block(0, emA, tgA);
#pragma unroll 1
  for (int k = 0; k < 128; k += 2){
    load_block(k + 1, emB, tgB);
    process_block(k, emA, tgA);
    load_block((k + 2 > 127) ? 127 : (k + 2), emA, tgA);
    process_block(k + 1, emB, tgB);
  }

  // tail: sequence runs to the very end -> end transition for tag at t=L-1
  if ((prevtag != 0) && (qr == 0)) num += s_end[prevtag - 1];

  // denominator: log( sum_j alpha[j] * exp(end[j]) ) + logZ
  float acc = master.x * fexp2(s_end[r0 + 0] * LOG2E)
            + master.y * fexp2(s_end[r0 + 1] * LOG2E)
            + master.z * fexp2(s_end[r0 + 2] * LOG2E)
            + master.w * fexp2(s_end[r0 + 3] * LOG2E);
  acc += __shfl_xor(acc, 16, 64);
  num += __shfl_xor(num, 16, 64);
  const float denom = (flog2(acc) + logZ) * LN2;

  if (qr == 0) atomicAdd(out, (denom - num) * (1.0f / 2048.0f));
}

extern "C" void kernel_launch(void* const* d_in, const int* in_sizes, int n_in,
                              void* d_out, int out_size, void* d_ws, size_t ws_size,
                              hipStream_t stream) {
  const float* em    = (const float*)d_in[0];
  const float* trans = (const float*)d_in[1];
  const float* strt  = (const float*)d_in[2];
  const float* endt  = (const float*)d_in[3];
  const int*   tags  = (const int*)d_in[4];
  float* out = (float*)d_out;

  hipMemsetAsync(out, 0, sizeof(float), stream);
  crf_fused<<<64, 64, 0, stream>>>(em, trans, strt, endt, tags, out);
}

// Round 2
// 283.002 us; speedup vs baseline: 1.9316x; 1.9316x over previous
//
#include <hip/hip_runtime.h>
#include <stdint.h>

typedef float  v4f __attribute__((ext_vector_type(4)));
typedef short  v4s __attribute__((ext_vector_type(4)));
typedef int    v4i __attribute__((ext_vector_type(4)));

#define LOG2E 1.44269504088896340736f
#define LN2   0.69314718055994530942f

static __device__ __forceinline__ float fexp2(float x){ return __builtin_amdgcn_exp2f(x); }
static __device__ __forceinline__ float flog2(float x){ return __builtin_amdgcn_logf(x); }

// pack two f32 -> two bf16 (round-half-up) in one dword via v_perm
static __device__ __forceinline__ unsigned pkbf(float a, float b){
  unsigned ua = __float_as_uint(a) + 0x8000u;
  unsigned ub = __float_as_uint(b) + 0x8000u;
  return __builtin_amdgcn_perm(ub, ua, 0x07060302u);
}
static __device__ __forceinline__ v4s pack4(const v4f& m){
  union { unsigned u[2]; v4s s; } t;
  t.u[0] = pkbf(m.x, m.y);
  t.u[1] = pkbf(m.z, m.w);
  return t.s;
}

static __device__ __forceinline__ v4f mfma16(v4s a, v4s b, v4f c){
#if __has_builtin(__builtin_amdgcn_mfma_f32_16x16x16bf16_1k)
  return __builtin_amdgcn_mfma_f32_16x16x16bf16_1k(a, b, c, 0, 0, 0);
#else
  v4f r = c;
  asm("s_nop 1\n\tv_mfma_f32_16x16x16_bf16 %0, %1, %2, %0\n\ts_nop 7\n\ts_nop 1"
      : "+v"(r) : "v"(a), "v"(b));
  return r;
#endif
}

// ---------------- Phase 1: per-(batch,chunk) 8x8 transfer-matrix products ----------------
// Wave handles 4 (b,c) pairs. B operand of 16x16x16 MFMA = 2 k-blocks x 2 column-octets:
//   matrix mm = ((q>>1)<<1)|(n>>3), lane holds P[rows r0..r0+3][col cn], r0=(q&1)*4, cn=n&7.
// Step: P' = diag(exp(em_t)) * E^T * P (per column, with per-column log2 scale carried out).
// D (C-layout) == next B (B-layout) index map -> zero-shuffle feedback.
__global__ __launch_bounds__(64, 1)
void crf_phase1(const float* __restrict__ em,
                const float* __restrict__ trans,
                const float* __restrict__ endt,
                const int*   __restrict__ tags,
                float* __restrict__ ws,
                int S, int nC)
{
  const int lane = threadIdx.x;
  const int n  = lane & 15;
  const int q  = lane >> 4;
  const int qr = q & 1;
  const int r0 = qr << 2;
  const int cn = n & 7;
  const int mm = ((q >> 1) << 1) | (n >> 3);
  const int p  = (blockIdx.x << 2) + mm;
  const int c  = p >> 11;          // chunk id (2048 batches)
  const int bm = p & 2047;         // batch id

  __shared__ float s_trans[64];
  __shared__ float s_end[8];
  s_trans[lane] = trans[lane];
  if (lane < 8) s_end[lane] = endt[lane];
  __syncthreads();

  // constant A fragment: blockdiag(E^T, E^T); A[m][k], m=n, k=4q+j
  v4s afrag;
  {
    float av[4];
#pragma unroll
    for (int j = 0; j < 4; ++j){
      const int k = (q << 2) + j;
      float v = 0.f;
      if (n < 8 && k < 8)        v = fexp2(s_trans[k * 8 + n] * LOG2E);
      else if (n >= 8 && k >= 8) v = fexp2(s_trans[(k - 8) * 8 + (n - 8)] * LOG2E);
      av[j] = v;
    }
    union { unsigned u[2]; v4s s; } t;
    t.u[0] = pkbf(av[0], av[1]);
    t.u[1] = pkbf(av[2], av[3]);
    afrag = t.s;
  }

  const float* emb = em   + ((size_t)bm * 2048u + (size_t)c * (unsigned)S) * 8u + (unsigned)r0;
  const int*   tgb = tags + (size_t)bm * 2048u + (size_t)c * (unsigned)S;

  // P = identity (exact in bf16)
  v4f master;
  master.x = (r0 + 0 == cn) ? 1.f : 0.f;
  master.y = (r0 + 1 == cn) ? 1.f : 0.f;
  master.z = (r0 + 2 == cn) ? 1.f : 0.f;
  master.w = (r0 + 3 == cn) ? 1.f : 0.f;
  v4s bfrag = pack4(master);

  float num = 0.f, lZ = 0.f;
  int prevtag = 0;
  if (c != 0) prevtag = tgb[-1];

  v4f emA[8], emB[8];
  v4i tgA[2], tgB[2];

  auto load8 = [&](int kb8, v4f* E, v4i* T){
    const int t0 = kb8 << 3;
#pragma unroll
    for (int j = 0; j < 8; ++j)
      E[j] = *(const v4f*)(emb + (size_t)(t0 + j) * 8u);
    T[0] = *(const v4i*)(tgb + t0);
    T[1] = *(const v4i*)(tgb + t0 + 4);
  };

  auto sel4 = [&](const v4f& e4, int s)->float{
    float a = (s & 1) ? e4.y : e4.x;
    float cc = (s & 1) ? e4.w : e4.z;
    return (s & 2) ? cc : a;
  };

  auto step = [&](const v4f& em4, int cur){
    v4f e;
    e.x = fexp2(em4.x * LOG2E); e.y = fexp2(em4.y * LOG2E);
    e.z = fexp2(em4.z * LOG2E); e.w = fexp2(em4.w * LOG2E);
    v4f zero = {0.f, 0.f, 0.f, 0.f};
    v4f d = mfma16(afrag, bfrag, zero);
    const bool m = (cur != 0);
    master.x = m ? d.x * e.x : master.x;
    master.y = m ? d.y * e.y : master.y;
    master.z = m ? d.z * e.z : master.z;
    master.w = m ? d.w * e.w : master.w;
    bfrag = pack4(master);
    // numerator (all 8 column-lanes compute identical copies; one stores)
    const int s = cur - 1;
    const float ev = sel4(em4, s);
    num += (m && ((s >> 2) == qr)) ? ev : 0.f;
    const float tv = s_trans[(((prevtag - 1) & 7) << 3) + (s & 7)];
    num += (m && (qr == 0)) ? tv : 0.f;
    if ((prevtag != 0) && (cur == 0) && (qr == 0)) num += s_end[prevtag - 1];
    prevtag = cur;
  };

  auto renorm = [&](){
    float mx = fmaxf(fmaxf(master.x, master.y), fmaxf(master.z, master.w));
    mx = fmaxf(mx, __shfl_xor(mx, 16, 64));      // column max across the q-pair
    const float inv = __builtin_amdgcn_rcpf(mx);
    master.x *= inv; master.y *= inv; master.z *= inv; master.w *= inv;
    lZ += flog2(mx);                              // per-column log2 scale
    bfrag = pack4(master);
  };

  auto proc8 = [&](const v4f* E, const v4i* T, bool skip0){
#pragma unroll
    for (int j = 0; j < 8; ++j){
      const int cur = T[j >> 2][j & 3];
      if (j == 0 && skip0) { prevtag = cur; continue; }  // t=0 handled in phase 2
      step(E[j], cur);
    }
  };

  const int nkb = S >> 3;
  load8(0, emA, tgA);
#pragma unroll 1
  for (int kb = 0; kb < nkb; kb += 2){
    load8(kb + 1, emB, tgB);
    proc8(emA, tgA, (c == 0) && (kb == 0));
    load8((kb + 2 < nkb) ? (kb + 2) : (nkb - 1), emA, tgA);
    proc8(emB, tgB, false);
    renorm();                                     // every 16 steps
  }

  // final tail: sequence runs to t = L-1
  if ((c == nC - 1) && (prevtag != 0) && (qr == 0)) num += s_end[prevtag - 1];

  float* base = ws + ((size_t)c * 2048u + (size_t)bm) * 80u;
  *(v4f*)(base + (cn * 8 + r0)) = master;         // entry e = col*8 + row
  if (qr == 0) base[64 + cn] = lZ;
  float numt = num + __shfl_xor(num, 16, 64);
  if (qr == 0 && cn == 0) base[72] = numt;
}

// ---------------- Phase 2: per-batch combine of chunk matrices ----------------
__global__ __launch_bounds__(64, 1)
void crf_phase2(const float* __restrict__ em,
                const float* __restrict__ strt,
                const float* __restrict__ endt,
                const int*   __restrict__ tags,
                const float* __restrict__ ws,
                float* __restrict__ out,
                int nC)
{
  const int lane = threadIdx.x;
  const int b = (blockIdx.x << 6) + lane;

  const float* em0 = em + (size_t)b * 16384u;
  float al[8];
#pragma unroll
  for (int i = 0; i < 8; ++i) al[i] = strt[i] + em0[i];
  const int tag0 = tags[(size_t)b * 2048u];
  const int s0 = tag0 - 1;
  float num = strt[s0] + em0[s0];

  float mx = al[0];
#pragma unroll
  for (int i = 1; i < 8; ++i) mx = fmaxf(mx, al[i]);
  float a[8];
#pragma unroll
  for (int i = 0; i < 8; ++i) a[i] = fexp2((al[i] - mx) * LOG2E);
  float lZ2 = mx * LOG2E;

  float P0[64], P1[64], ls0[8], ls1[8], nm0, nm1;

  auto loadC = [&](int c, float* P, float* ls, float& nm){
    const float* base = ws + ((size_t)c * 2048u + (size_t)b) * 80u;
#pragma unroll
    for (int i = 0; i < 16; ++i) *(v4f*)&P[i * 4] = *(const v4f*)(base + i * 4);
    *(v4f*)&ls[0] = *(const v4f*)(base + 64);
    *(v4f*)&ls[4] = *(const v4f*)(base + 68);
    nm = base[72];
  };

  auto fold = [&](const float* P, const float* ls, float nm){
    float lm = ls[0];
#pragma unroll
    for (int i = 1; i < 8; ++i) lm = fmaxf(lm, ls[i]);
    float w[8];
#pragma unroll
    for (int i = 0; i < 8; ++i) w[i] = a[i] * fexp2(ls[i] - lm);
    float acc[8] = {0.f,0.f,0.f,0.f,0.f,0.f,0.f,0.f};
#pragma unroll
    for (int i = 0; i < 8; ++i)
#pragma unroll
      for (int j = 0; j < 8; ++j)
        acc[j] += w[i] * P[i * 8 + j];            // alpha'[j] = sum_i w_i P[j][i], e=i*8+j
    float m2 = acc[0];
#pragma unroll
    for (int j = 1; j < 8; ++j) m2 = fmaxf(m2, acc[j]);
    const float inv = __builtin_amdgcn_rcpf(m2);
#pragma unroll
    for (int j = 0; j < 8; ++j) a[j] = acc[j] * inv;
    lZ2 += lm + flog2(m2);
    num += nm;
  };

  loadC(0, P0, ls0, nm0);
#pragma unroll 1
  for (int c = 0; c < nC; c += 2){
    loadC(c + 1, P1, ls1, nm1);
    fold(P0, ls0, nm0);
    loadC((c + 2 < nC) ? (c + 2) : (c + 1), P0, ls0, nm0);
    fold(P1, ls1, nm1);
  }

  float accf = 0.f;
#pragma unroll
  for (int j = 0; j < 8; ++j) accf += a[j] * fexp2(endt[j] * LOG2E);
  const float denom = (flog2(accf) + lZ2) * LN2;
  float contrib = (denom - num) * (1.0f / 2048.0f);

#pragma unroll
  for (int off = 32; off; off >>= 1) contrib += __shfl_down(contrib, off, 64);
  if (lane == 0) atomicAdd(out, contrib);
}

extern "C" void kernel_launch(void* const* d_in, const int* in_sizes, int n_in,
                              void* d_out, int out_size, void* d_ws, size_t ws_size,
                              hipStream_t stream) {
  const float* em    = (const float*)d_in[0];
  const float* trans = (const float*)d_in[1];
  const float* strt  = (const float*)d_in[2];
  const float* endt  = (const float*)d_in[3];
  const int*   tags  = (const int*)d_in[4];
  float* out = (float*)d_out;

  const size_t per_chunk = (size_t)2048 * 80 * 4;  // bytes per chunk-plane
  int C;
  if      (ws_size >= 32 * per_chunk) C = 32;      // 21.0 MB
  else if (ws_size >= 16 * per_chunk) C = 16;
  else if (ws_size >=  8 * per_chunk) C = 8;
  else                                C = 4;
  const int S = 2048 / C;

  hipMemsetAsync(out, 0, sizeof(float), stream);
  crf_phase1<<<512 * C, 64, 0, stream>>>(em, trans, endt, tags, (float*)d_ws, S, C);
  crf_phase2<<<32, 64, 0, stream>>>(em, strt, endt, tags, (const float*)d_ws, out, C);
}

// Round 3
// 265.022 us; speedup vs baseline: 2.0627x; 1.0678x over previous
//
#include <hip/hip_runtime.h>
#include <stdint.h>

typedef float  v4f __attribute__((ext_vector_type(4)));
typedef short  v4s __attribute__((ext_vector_type(4)));
typedef int    v4i __attribute__((ext_vector_type(4)));

#define LOG2E 1.44269504088896340736f
#define LN2   0.69314718055994530942f

static __device__ __forceinline__ float fexp2(float x){ return __builtin_amdgcn_exp2f(x); }
static __device__ __forceinline__ float flog2(float x){ return __builtin_amdgcn_logf(x); }

// pack two f32 -> two bf16 (round-half-up) in one dword via v_perm
static __device__ __forceinline__ unsigned pkbf(float a, float b){
  unsigned ua = __float_as_uint(a) + 0x8000u;
  unsigned ub = __float_as_uint(b) + 0x8000u;
  return __builtin_amdgcn_perm(ub, ua, 0x07060302u);
}
static __device__ __forceinline__ v4s pack4(const v4f& m){
  union { unsigned u[2]; v4s s; } t;
  t.u[0] = pkbf(m.x, m.y);
  t.u[1] = pkbf(m.z, m.w);
  return t.s;
}

static __device__ __forceinline__ v4f mfma16(v4s a, v4s b, v4f c){
#if __has_builtin(__builtin_amdgcn_mfma_f32_16x16x16bf16_1k)
  return __builtin_amdgcn_mfma_f32_16x16x16bf16_1k(a, b, c, 0, 0, 0);
#else
  v4f r = c;
  asm("s_nop 1\n\tv_mfma_f32_16x16x16_bf16 %0, %1, %2, %0\n\ts_nop 7\n\ts_nop 1"
      : "+v"(r) : "v"(a), "v"(b));
  return r;
#endif
}

static __device__ __forceinline__ float sel4(const v4f& e4, int s){
  float a = (s & 1) ? e4.y : e4.x;
  float c = (s & 1) ? e4.w : e4.z;
  return (s & 2) ? c : a;
}

// ---------------- Phase 1 ----------------
// 4 (batch,chunk) 8x8 transfer-matrix products per wave via one 16x16x16 bf16 MFMA.
// Lane roles: n=lane&15, q=lane>>4, qr=q&1 (row half, r0=4*qr), cn=n&7 (column),
// matrix mm=((q>>1)<<1)|(n>>3). Recurrence P' = diag(exp(em_t)) * E^T * P.
// D (C-layout) == next B (B-layout) -> zero-shuffle feedback.
// exp/numerator work distributed by step across the 8 column lanes; exps broadcast
// through a wave-local LDS slot (no barrier needed: per-wave DS ops are in order).

template<bool MASKED>
__device__ __forceinline__ void chunk_loop(
    const float* __restrict__ emb, const int* __restrict__ tgb, int nkb, int c,
    const float* s_trans, const float* s_end, float* s_slot,
    v4s afrag, int qr, int r0, int cn, bool lastChunk,
    v4f& master, v4s& bfrag, float& lZ, float& num)
{
  v4f eoA, eoB; v4i tA0 = {}, tA1 = {}, tB0 = {}, tB1 = {};
  int tcA = 0, tpA = 0, tcB = 0, tpB = 0;

  auto loadK = [&](int kb, v4f& eo, v4i& t0v, v4i& t1v, int& tc, int& tp){
    const int t0 = kb << 3;
    eo = *(const v4f*)(emb + (size_t)(t0 + cn) * 8u);
    if (MASKED){
      t0v = *(const v4i*)(tgb + t0);
      t1v = *(const v4i*)(tgb + t0 + 4);
    }
    tc = tgb[t0 + cn];
    int ip = t0 + cn - 1;
    if (!MASKED && c == 0 && ip < 0) ip = 0;   // avoid OOB at global t=0 (value unused)
    tp = tgb[ip];
  };

  auto procK = [&](int kb, const v4f& eo, const v4i& t0v, const v4i& t1v,
                   int tc, int tp, bool skipFirst){
    // distributed exps: this lane covers step t0+cn, rows r0..r0+3
    v4f ed;
    ed.x = fexp2(eo.x * LOG2E); ed.y = fexp2(eo.y * LOG2E);
    ed.z = fexp2(eo.z * LOG2E); ed.w = fexp2(eo.w * LOG2E);
    float* sl = s_slot + ((kb & 1) << 5);
    *(v4f*)(sl + (cn << 2)) = ed;              // ds_write_b128
    v4f e8[8];
#pragma unroll
    for (int j = 0; j < 8; ++j) e8[j] = *(const v4f*)(sl + (j << 2));

    // distributed numerator for step t = kb*8 + cn
    {
      bool act = MASKED ? (tc != 0) : true;
      const bool sk0 = (!MASKED) && (c == 0) && (kb == 0) && (cn == 0);
      if (sk0) act = false;
      const int s = tc - 1;
      const float ev = sel4(eo, s);
      num += (act && ((s >> 2) == qr)) ? ev : 0.f;
      const float tv = s_trans[(((tp - 1) & 7) << 3) + (s & 7)];
      num += (act && (qr == 0)) ? tv : 0.f;
      if (MASKED){
        if ((tp != 0) && (tc == 0) && (qr == 0)) num += s_end[tp - 1];
      }
    }

    // 8 recurrence steps
#pragma unroll
    for (int j = 0; j < 8; ++j){
      if (skipFirst && j == 0) continue;       // global t=0 handled in phase 2
      v4f zero = {0.f, 0.f, 0.f, 0.f};
      v4f d = mfma16(afrag, bfrag, zero);
      const v4f e = e8[j];
      if (MASKED){
        const int ct = (j < 4) ? t0v[j] : t1v[j - 4];
        const bool m = (ct != 0);
        master.x = m ? d.x * e.x : master.x;
        master.y = m ? d.y * e.y : master.y;
        master.z = m ? d.z * e.z : master.z;
        master.w = m ? d.w * e.w : master.w;
      } else {
        master.x = d.x * e.x; master.y = d.y * e.y;
        master.z = d.z * e.z; master.w = d.w * e.w;
      }
      bfrag = pack4(master);
    }
  };

  auto renorm = [&](){
    float mx = fmaxf(fmaxf(master.x, master.y), fmaxf(master.z, master.w));
    mx = fmaxf(mx, __shfl_xor(mx, 16, 64));    // column max across the qr pair
    const float inv = __builtin_amdgcn_rcpf(mx);
    master.x *= inv; master.y *= inv; master.z *= inv; master.w *= inv;
    lZ += flog2(mx);
    bfrag = pack4(master);
  };

  loadK(0, eoA, tA0, tA1, tcA, tpA);
#pragma unroll 1
  for (int kb = 0; kb < nkb; kb += 2){
    loadK(kb + 1, eoB, tB0, tB1, tcB, tpB);
    procK(kb, eoA, tA0, tA1, tcA, tpA, (!MASKED) && (c == 0) && (kb == 0));
    if (kb + 2 < nkb) loadK(kb + 2, eoA, tA0, tA1, tcA, tpA);
    procK(kb + 1, eoB, tB0, tB1, tcB, tpB, false);
    renorm();                                  // every 16 steps
  }

  if (MASKED && lastChunk){
    const int lt = tgb[(nkb << 3) - 1];        // tag at global t = L-1
    if ((lt != 0) && (qr == 0) && (cn == 0)) num += s_end[lt - 1];
  }
}

__global__ __launch_bounds__(256, 4)
void crf_phase1(const float* __restrict__ em,
                const float* __restrict__ trans,
                const float* __restrict__ endt,
                const int*   __restrict__ tags,
                float* __restrict__ ws,
                int S, int nC)
{
  const int tid  = threadIdx.x;
  const int lane = tid & 63;
  const int n = lane & 15, q = lane >> 4, qr = q & 1, r0 = qr << 2, cn = n & 7;
  const int mm = ((q >> 1) << 1) | (n >> 3);
  const int p  = (blockIdx.x << 4) + ((tid >> 6) << 2) + mm;
  const int c  = p >> 11;          // chunk id
  const int bm = p & 2047;         // batch id

  __shared__ float s_trans[64];
  __shared__ float s_end[8];
  __shared__ float s_e[32 * 68];   // 32 groups x (2 bufs x 32 floats + 4 pad)
  if (tid < 64) s_trans[tid] = trans[tid];
  if (tid < 8)  s_end[tid]  = endt[tid];
  __syncthreads();

  // constant A fragment: blockdiag(E^T, E^T); A[m][k], m=n, k=4q+j
  v4s afrag;
  {
    float av[4];
#pragma unroll
    for (int j = 0; j < 4; ++j){
      const int k = (q << 2) + j;
      float v = 0.f;
      if (n < 8 && k < 8)        v = fexp2(s_trans[k * 8 + n] * LOG2E);
      else if (n >= 8 && k >= 8) v = fexp2(s_trans[(k - 8) * 8 + (n - 8)] * LOG2E);
      av[j] = v;
    }
    union { unsigned u[2]; v4s s; } t;
    t.u[0] = pkbf(av[0], av[1]);
    t.u[1] = pkbf(av[2], av[3]);
    afrag = t.s;
  }

  const float* emb = em   + ((size_t)bm * 2048u + (size_t)c * (unsigned)S) * 8u + (unsigned)r0;
  const int*   tgb = tags + (size_t)bm * 2048u + (size_t)c * (unsigned)S;
  float* s_slot = &s_e[(tid >> 3) * 68];

  // P = identity
  v4f master;
  master.x = (r0 + 0 == cn) ? 1.f : 0.f;
  master.y = (r0 + 1 == cn) ? 1.f : 0.f;
  master.z = (r0 + 2 == cn) ? 1.f : 0.f;
  master.w = (r0 + 3 == cn) ? 1.f : 0.f;
  v4s bfrag = pack4(master);
  float num = 0.f, lZ = 0.f;

  const bool maskless = ((c + 1) * S <= 1024);   // lengths >= L/2: never masked
  const int  nkb = S >> 3;

  if (maskless){
    chunk_loop<false>(emb, tgb, nkb, c, s_trans, s_end, s_slot,
                      afrag, qr, r0, cn, false, master, bfrag, lZ, num);
  } else {
    // whole-wave skip when all 4 chunks are fully masked (mask is monotone)
    const bool fz = (tgb[0] == 0);
    if (__ballot(fz) == ~0ull){
      const int pv = tgb[-1];                    // c >= 16 here, always valid
      if ((pv != 0) && (qr == 0) && (cn == 0)) num = s_end[pv - 1];
      // master stays identity, lZ stays 0
    } else {
      chunk_loop<true>(emb, tgb, nkb, c, s_trans, s_end, s_slot,
                       afrag, qr, r0, cn, (c == nC - 1), master, bfrag, lZ, num);
    }
  }

  // ---- store, [c][entry-pair][b] layout (phase-2 coalescing) ----
  float2* ws2 = ((float2*)ws) + (size_t)c * 40u * 2048u + (unsigned)bm;
  const int e0 = (cn << 3) + r0;                 // even
  float2 v01; v01.x = master.x; v01.y = master.y;
  float2 v23; v23.x = master.z; v23.y = master.w;
  ws2[(size_t)(e0 >> 1) * 2048u]       = v01;
  ws2[(size_t)((e0 >> 1) + 1) * 2048u] = v23;
  if (qr == 0){
    const int ep = (64 + cn) >> 1;
    ((float*)(ws2 + (size_t)ep * 2048u))[cn & 1] = lZ;
  }
  num += __shfl_xor(num, 1, 64);
  num += __shfl_xor(num, 2, 64);
  num += __shfl_xor(num, 4, 64);
  num += __shfl_xor(num, 16, 64);
  if (qr == 0 && cn == 0)
    ((float*)(ws2 + (size_t)36 * 2048u))[0] = num;
}

// ---------------- Phase 2: per-batch combine of chunk matrices ----------------
__global__ __launch_bounds__(64, 1)
void crf_phase2(const float* __restrict__ em,
                const float* __restrict__ strt,
                const float* __restrict__ endt,
                const int*   __restrict__ tags,
                const float* __restrict__ ws,
                float* __restrict__ out,
                int nC)
{
  const int lane = threadIdx.x;
  const int b = (blockIdx.x << 6) + lane;

  const float* em0 = em + (size_t)b * 16384u;
  float al[8];
#pragma unroll
  for (int i = 0; i < 8; ++i) al[i] = strt[i] + em0[i];
  const int tag0 = tags[(size_t)b * 2048u];
  const int s0 = tag0 - 1;
  float num = strt[s0] + em0[s0];

  float mx = al[0];
#pragma unroll
  for (int i = 1; i < 8; ++i) mx = fmaxf(mx, al[i]);
  float a[8];
#pragma unroll
  for (int i = 0; i < 8; ++i) a[i] = fexp2((al[i] - mx) * LOG2E);
  float lZ2 = mx * LOG2E;

  float P0[64], P1[64], ls0[8], ls1[8], nm0, nm1;

  auto loadC = [&](int c, float* P, float* ls, float& nm){
    const float2* base = ((const float2*)ws) + (size_t)c * 40u * 2048u + (unsigned)b;
#pragma unroll
    for (int i2 = 0; i2 < 32; ++i2){
      float2 v = base[(size_t)i2 * 2048u];
      P[2 * i2] = v.x; P[2 * i2 + 1] = v.y;
    }
#pragma unroll
    for (int k = 0; k < 4; ++k){
      float2 v = base[(size_t)(32 + k) * 2048u];
      ls[2 * k] = v.x; ls[2 * k + 1] = v.y;
    }
    nm = base[(size_t)36 * 2048u].x;
  };

  auto fold = [&](const float* P, const float* ls, float nm){
    float lm = ls[0];
#pragma unroll
    for (int i = 1; i < 8; ++i) lm = fmaxf(lm, ls[i]);
    float w[8];
#pragma unroll
    for (int i = 0; i < 8; ++i) w[i] = a[i] * fexp2(ls[i] - lm);
    float acc[8] = {0.f,0.f,0.f,0.f,0.f,0.f,0.f,0.f};
#pragma unroll
    for (int i = 0; i < 8; ++i)
#pragma unroll
      for (int j = 0; j < 8; ++j)
        acc[j] += w[i] * P[i * 8 + j];          // alpha'[row j] += w[col i] * P[col i][row j]
    float m2 = acc[0];
#pragma unroll
    for (int j = 1; j < 8; ++j) m2 = fmaxf(m2, acc[j]);
    const float inv = __builtin_amdgcn_rcpf(m2);
#pragma unroll
    for (int j = 0; j < 8; ++j) a[j] = acc[j] * inv;
    lZ2 += lm + flog2(m2);
    num += nm;
  };

  loadC(0, P0, ls0, nm0);
#pragma unroll 1
  for (int c = 0; c < nC; c += 2){
    loadC(c + 1, P1, ls1, nm1);
    fold(P0, ls0, nm0);
    loadC((c + 2 < nC) ? (c + 2) : (c + 1), P0, ls0, nm0);
    fold(P1, ls1, nm1);
  }

  float accf = 0.f;
#pragma unroll
  for (int j = 0; j < 8; ++j) accf += a[j] * fexp2(endt[j] * LOG2E);
  const float denom = (flog2(accf) + lZ2) * LN2;
  float contrib = (denom - num) * (1.0f / 2048.0f);

#pragma unroll
  for (int off = 32; off; off >>= 1) contrib += __shfl_down(contrib, off, 64);
  if (lane == 0) atomicAdd(out, contrib);
}

extern "C" void kernel_launch(void* const* d_in, const int* in_sizes, int n_in,
                              void* d_out, int out_size, void* d_ws, size_t ws_size,
                              hipStream_t stream) {
  const float* em    = (const float*)d_in[0];
  const float* trans = (const float*)d_in[1];
  const float* strt  = (const float*)d_in[2];
  const float* endt  = (const float*)d_in[3];
  const int*   tags  = (const int*)d_in[4];
  float* out = (float*)d_out;

  const size_t per_chunk = (size_t)2048 * 80 * 4;  // bytes per chunk-plane
  int C;
  if      (ws_size >= 32 * per_chunk) C = 32;      // 21.0 MB
  else if (ws_size >= 16 * per_chunk) C = 16;
  else if (ws_size >=  8 * per_chunk) C = 8;
  else                                C = 4;
  const int S = 2048 / C;

  hipMemsetAsync(out, 0, sizeof(float), stream);
  crf_phase1<<<128 * C, 256, 0, stream>>>(em, trans, endt, tags, (float*)d_ws, S, C);
  crf_phase2<<<32, 64, 0, stream>>>(em, strt, endt, tags, (const float*)d_ws, out, C);
}